// Round 10
// baseline (159.807 us; speedup 1.0000x reference)
//
#include <hip/hip_runtime.h>

#define N_NODES 100000
#define N_EDGES 1280000
#define DIM 64
#define NBINS 391          // nodes binned by dst>>8 (256 nodes/bin)
#define CAP 3712           // bin mean 3274, sd 57 -> +7.6 sd
#define EPB 4096           // edges per fill block
#define NFB 313            // ceil(N_EDGES / EPB)
#define CONVB 512          // conv blocks appended after the NFB fill blocks
#define NTILES 1563        // ceil(N_NODES / 64)
#define FPAD 68            // feat tile leading dim (64+4): keeps b128 align, 2-way banks
#define WSCALE (1.0f / 32767.0f)

__device__ __forceinline__ unsigned bf16_rne(float x) {
    unsigned u = __float_as_uint(x);
    return (u + 0x7fffu + ((u >> 16) & 1u)) >> 16;
}
__device__ __forceinline__ float bf_lo(unsigned q) { return __uint_as_float(q << 16); }
__device__ __forceinline__ float bf_hi(unsigned q) { return __uint_as_float(q & 0xffff0000u); }

// ---- fused: blocks [0,NFB) bucket edges; blocks [NFB,NFB+CONVB) compute fW=bf16(feat@W)
// as an LDS-tiled GEMM (R9: fixed the R7/R8 wcol-spill; VGPR-lean by design).
__global__ __launch_bounds__(256) void k_fill_conv(
    const int* __restrict__ src, const float* __restrict__ w,
    const int* __restrict__ dst, int* __restrict__ cursor,
    uint2* __restrict__ binned,
    const float* __restrict__ feat, const float* __restrict__ W,
    unsigned short* __restrict__ fW) {
    __shared__ union U {
        struct { int h[NBINS]; int base_[NBINS]; } fill;
        struct { float w[DIM * DIM]; float f[64 * FPAD]; } conv;
        __device__ U() {}
    } sm;
    int t = threadIdx.x;

    if (blockIdx.x < NFB) {
        // ---------------- fill half ----------------
        for (int i = t; i < NBINS; i += 256) sm.fill.h[i] = 0;
        __syncthreads();
        int eb = blockIdx.x * EPB;
        int d[16], sv[16];
        unsigned wq[16];
        #pragma unroll
        for (int j = 0; j < 16; ++j) {
            int e = eb + j * 256 + t;
            if (e < N_EDGES) {
                d[j] = dst[e];
                sv[j] = src[e];
                wq[j] = (unsigned)(w[e] * 32767.0f + 0.5f);
                atomicAdd(&sm.fill.h[d[j] >> 8], 1);
            } else d[j] = -1;
        }
        __syncthreads();
        for (int i = t; i < NBINS; i += 256) {
            int c = sm.fill.h[i];
            sm.fill.base_[i] = c ? atomicAdd(&cursor[i], c) : 0;
            sm.fill.h[i] = 0;   // reuse as local cursor
        }
        __syncthreads();
        #pragma unroll
        for (int j = 0; j < 16; ++j) {
            if (d[j] >= 0) {
                int bin = d[j] >> 8;
                int pos = sm.fill.base_[bin] + atomicAdd(&sm.fill.h[bin], 1);
                binned[bin * CAP + pos] =
                    make_uint2((unsigned)sv[j] | ((unsigned)(d[j] & 255) << 17), wq[j]);
            }
        }
    } else {
        // ---------------- conv half: fW = bf16(feat @ W), LDS-tiled ----------------
        #pragma unroll
        for (int i = 0; i < DIM * DIM / 256; ++i)
            sm.conv.w[t + i * 256] = W[t + i * 256];
        const float4* lds_w4 = (const float4*)sm.conv.w;
        float4* lds_f4 = (float4*)sm.conv.f;
        int tx = t & 15, ny = t >> 4;       // thread tile: nodes ny*4..+3, outs tx*4..+3
        int rr = t >> 2, seg = t & 3;       // staging: row rr, 16-float segment seg

        for (int tb = blockIdx.x - NFB; tb < NTILES; tb += CONVB) {
            int nb = tb * 64;
            __syncthreads();   // protect lds_f from previous tile's readers (also fences W stage)
            #pragma unroll
            for (int q = 0; q < 4; ++q) {
                float4 v = (nb + rr < N_NODES)
                           ? ((const float4*)feat)[(size_t)(nb + rr) * 16 + seg * 4 + q]
                           : make_float4(0.f, 0.f, 0.f, 0.f);
                lds_f4[(rr * FPAD + seg * 16 + q * 4) >> 2] = v;
            }
            __syncthreads();
            float acc[4][4];
            #pragma unroll
            for (int i = 0; i < 4; ++i)
                #pragma unroll
                for (int j = 0; j < 4; ++j) acc[i][j] = 0.f;
            for (int k0 = 0; k0 < DIM; k0 += 4) {
                float4 hv[4], wv[4];
                #pragma unroll
                for (int i = 0; i < 4; ++i)
                    hv[i] = lds_f4[((ny * 4 + i) * FPAD + k0) >> 2];
                #pragma unroll
                for (int j = 0; j < 4; ++j)
                    wv[j] = lds_w4[((k0 + j) * DIM + tx * 4) >> 2];
                #pragma unroll
                for (int i = 0; i < 4; ++i) {
                    const float* hp = (const float*)&hv[i];
                    #pragma unroll
                    for (int kk = 0; kk < 4; ++kk) {
                        float hk = hp[kk];
                        acc[i][0] = fmaf(hk, ((const float*)&wv[kk])[0], acc[i][0]);
                        acc[i][1] = fmaf(hk, ((const float*)&wv[kk])[1], acc[i][1]);
                        acc[i][2] = fmaf(hk, ((const float*)&wv[kk])[2], acc[i][2]);
                        acc[i][3] = fmaf(hk, ((const float*)&wv[kk])[3], acc[i][3]);
                    }
                }
            }
            #pragma unroll
            for (int i = 0; i < 4; ++i) {
                int node = nb + ny * 4 + i;
                if (node < N_NODES) {
                    ushort4 o;
                    o.x = (unsigned short)bf16_rne(acc[i][0]);
                    o.y = (unsigned short)bf16_rne(acc[i][1]);
                    o.z = (unsigned short)bf16_rne(acc[i][2]);
                    o.w = (unsigned short)bf16_rne(acc[i][3]);
                    *(ushort4*)(fW + (size_t)node * DIM + tx * 4) = o;
                }
            }
        }
    }
}

// ---- fused sort + gather: block = bin (512 thr). Sort edges into LDS stage,
// then 8 waves gather directly from LDS (no csrp/offs/cnt global round-trip). ----
__global__ __launch_bounds__(512) void k_sortgather(
    const uint2* __restrict__ binned, const int* __restrict__ cursor,
    const uint4* __restrict__ fW4, float* __restrict__ out) {
    __shared__ int h[256];
    __shared__ int excl[256];
    __shared__ unsigned stage[CAP];
    int b = blockIdx.x, t = threadIdx.x;
    int total = cursor[b];
    const uint2* seg = binned + b * CAP;

    // histogram over local node id
    if (t < 256) h[t] = 0;
    __syncthreads();
    for (int i = t; i < total; i += 512)
        atomicAdd(&h[(seg[i].x >> 17) & 255], 1);
    __syncthreads();
    // exclusive scan (first 256 threads active; barriers hit by all)
    int v = 0;
    if (t < 256) { v = h[t]; excl[t] = v; }
    __syncthreads();
    for (int off = 1; off < 256; off <<= 1) {
        int add = 0;
        if (t < 256 && t >= off) add = excl[t - off];
        __syncthreads();
        if (t < 256) excl[t] += add;
        __syncthreads();
    }
    if (t < 256) { excl[t] -= v; h[t] = 0; }   // h reused as scatter cursor
    __syncthreads();
    // scatter into stage (packed src17|w15)
    for (int i = t; i < total; i += 512) {
        uint2 e = seg[i];
        int o = (e.x >> 17) & 255;
        int pos = excl[o] + atomicAdd(&h[o], 1);
        if (pos < CAP) stage[pos] = (e.x & 0x1ffffu) | (e.y << 17);
    }
    __syncthreads();
    // gather: wave = node; 8 groups of 8 lanes; lane s covers dims 8s..8s+7.
    // h[loc] now holds cnt, excl[loc] the segment start — both LDS broadcasts.
    int lane = t & 63, wv = t >> 6;
    int g = lane >> 3, s = lane & 7;
    for (int loc = wv; loc < 256; loc += 8) {
        int node = (b << 8) + loc;
        if (node >= N_NODES) break;   // loc is wave-uniform
        int st = excl[loc];
        int c = h[loc];
        int en = st + c;
        float a[8] = {0, 0, 0, 0, 0, 0, 0, 0};
        for (int i = st; i < en; i += 16) {
            int i0 = i + g, i1 = i + 8 + g;
            unsigned p0 = stage[(i0 < en) ? i0 : st];
            unsigned p1 = stage[(i1 < en) ? i1 : st];
            float w0 = (i0 < en) ? (float)(p0 >> 17) * WSCALE : 0.f;
            float w1 = (i1 < en) ? (float)(p1 >> 17) * WSCALE : 0.f;
            uint4 q0 = fW4[((p0 & 0x1ffffu) << 3) + s];
            uint4 q1 = fW4[((p1 & 0x1ffffu) << 3) + s];
            a[0] = fmaf(bf_lo(q0.x), w0, a[0]); a[1] = fmaf(bf_hi(q0.x), w0, a[1]);
            a[2] = fmaf(bf_lo(q0.y), w0, a[2]); a[3] = fmaf(bf_hi(q0.y), w0, a[3]);
            a[4] = fmaf(bf_lo(q0.z), w0, a[4]); a[5] = fmaf(bf_hi(q0.z), w0, a[5]);
            a[6] = fmaf(bf_lo(q0.w), w0, a[6]); a[7] = fmaf(bf_hi(q0.w), w0, a[7]);
            a[0] = fmaf(bf_lo(q1.x), w1, a[0]); a[1] = fmaf(bf_hi(q1.x), w1, a[1]);
            a[2] = fmaf(bf_lo(q1.y), w1, a[2]); a[3] = fmaf(bf_hi(q1.y), w1, a[3]);
            a[4] = fmaf(bf_lo(q1.z), w1, a[4]); a[5] = fmaf(bf_hi(q1.z), w1, a[5]);
            a[6] = fmaf(bf_lo(q1.w), w1, a[6]); a[7] = fmaf(bf_hi(q1.w), w1, a[7]);
        }
        #pragma unroll
        for (int j = 0; j < 8; ++j) {
            a[j] += __shfl_xor(a[j], 8, 64);
            a[j] += __shfl_xor(a[j], 16, 64);
            a[j] += __shfl_xor(a[j], 32, 64);
        }
        float dinv = 1.0f / fmaxf((float)c, 1.0f);
        if (g == 0) {   // lanes 0..7: lane s holds dims 8s..8s+7
            float4 o0, o1;
            o0.x = a[0] * dinv; o0.y = a[1] * dinv; o0.z = a[2] * dinv; o0.w = a[3] * dinv;
            o1.x = a[4] * dinv; o1.y = a[5] * dinv; o1.z = a[6] * dinv; o1.w = a[7] * dinv;
            ((float4*)out)[node * 16 + s * 2 + 0] = o0;
            ((float4*)out)[node * 16 + s * 2 + 1] = o1;
        }
    }
}

extern "C" void kernel_launch(void* const* d_in, const int* in_sizes, int n_in,
                              void* d_out, int out_size, void* d_ws, size_t ws_size,
                              hipStream_t stream) {
    const float* feat = (const float*)d_in[0];
    const float* w    = (const float*)d_in[1];
    const float* W    = (const float*)d_in[2];
    const int*   src  = (const int*)d_in[3];
    const int*   dst  = (const int*)d_in[4];
    float* out = (float*)d_out;

    // ~24.5 MB total (ws is 256 MiB). fill and conv outputs are disjoint.
    unsigned short* fW = (unsigned short*)d_ws;                  // 12.8 MB, 16B-aligned
    uint2* binned  = (uint2*)(fW + (size_t)N_NODES * DIM);       // NBINS*CAP*8 = 11.6 MB
    int* cursor    = (int*)(binned + (size_t)NBINS * CAP);       // NBINS

    hipMemsetAsync(cursor, 0, NBINS * sizeof(int), stream);

    k_fill_conv<<<NFB + CONVB, 256, 0, stream>>>(src, w, dst, cursor, binned,
                                                 feat, W, fW);
    k_sortgather<<<NBINS, 512, 0, stream>>>(binned, cursor, (const uint4*)fW, out);
}

// Round 11
// 150.191 us; speedup vs baseline: 1.0640x; 1.0640x over previous
//
#include <hip/hip_runtime.h>

#define N_NODES 100000
#define N_EDGES 1280000
#define DIM 64
#define NBINS 391          // nodes binned by dst>>8 (256 nodes/bin)
#define CAP 3712           // bin mean 3274, sd 57 -> +7.6 sd
#define EPB 4096           // edges per fill block
#define NFB 313            // ceil(N_EDGES / EPB)
#define CONVB 512          // conv blocks appended after the NFB fill blocks
#define NTILES 1563        // ceil(N_NODES / 64)
#define FPAD 68            // feat tile leading dim (64+4): keeps b128 align, 2-way banks
#define WSCALE (1.0f / 32767.0f)

__device__ __forceinline__ unsigned bf16_rne(float x) {
    unsigned u = __float_as_uint(x);
    return (u + 0x7fffu + ((u >> 16) & 1u)) >> 16;
}
__device__ __forceinline__ float bf_lo(unsigned q) { return __uint_as_float(q << 16); }
__device__ __forceinline__ float bf_hi(unsigned q) { return __uint_as_float(q & 0xffff0000u); }

// ---- fused: blocks [0,NFB) bucket edges; blocks [NFB,NFB+CONVB) compute fW=bf16(feat@W)
// as an LDS-tiled GEMM (R9: fixed the R7/R8 wcol-spill; VGPR-lean by design).
__global__ __launch_bounds__(256) void k_fill_conv(
    const int* __restrict__ src, const float* __restrict__ w,
    const int* __restrict__ dst, int* __restrict__ cursor,
    uint2* __restrict__ binned,
    const float* __restrict__ feat, const float* __restrict__ W,
    unsigned short* __restrict__ fW) {
    __shared__ union U {
        struct { int h[NBINS]; int base_[NBINS]; } fill;
        struct { float w[DIM * DIM]; float f[64 * FPAD]; } conv;
        __device__ U() {}
    } sm;
    int t = threadIdx.x;

    if (blockIdx.x < NFB) {
        // ---------------- fill half ----------------
        for (int i = t; i < NBINS; i += 256) sm.fill.h[i] = 0;
        __syncthreads();
        int eb = blockIdx.x * EPB;
        int d[16], sv[16];
        unsigned wq[16];
        #pragma unroll
        for (int j = 0; j < 16; ++j) {
            int e = eb + j * 256 + t;
            if (e < N_EDGES) {
                d[j] = dst[e];
                sv[j] = src[e];
                wq[j] = (unsigned)(w[e] * 32767.0f + 0.5f);
                atomicAdd(&sm.fill.h[d[j] >> 8], 1);
            } else d[j] = -1;
        }
        __syncthreads();
        for (int i = t; i < NBINS; i += 256) {
            int c = sm.fill.h[i];
            sm.fill.base_[i] = c ? atomicAdd(&cursor[i], c) : 0;
            sm.fill.h[i] = 0;   // reuse as local cursor
        }
        __syncthreads();
        #pragma unroll
        for (int j = 0; j < 16; ++j) {
            if (d[j] >= 0) {
                int bin = d[j] >> 8;
                int pos = sm.fill.base_[bin] + atomicAdd(&sm.fill.h[bin], 1);
                binned[bin * CAP + pos] =
                    make_uint2((unsigned)sv[j] | ((unsigned)(d[j] & 255) << 17), wq[j]);
            }
        }
    } else {
        // ---------------- conv half: fW = bf16(feat @ W), LDS-tiled ----------------
        #pragma unroll
        for (int i = 0; i < DIM * DIM / 256; ++i)
            sm.conv.w[t + i * 256] = W[t + i * 256];
        const float4* lds_w4 = (const float4*)sm.conv.w;
        float4* lds_f4 = (float4*)sm.conv.f;
        int tx = t & 15, ny = t >> 4;       // thread tile: nodes ny*4..+3, outs tx*4..+3
        int rr = t >> 2, seg = t & 3;       // staging: row rr, 16-float segment seg

        for (int tb = blockIdx.x - NFB; tb < NTILES; tb += CONVB) {
            int nb = tb * 64;
            __syncthreads();   // protect lds_f from previous tile's readers (also fences W stage)
            #pragma unroll
            for (int q = 0; q < 4; ++q) {
                float4 v = (nb + rr < N_NODES)
                           ? ((const float4*)feat)[(size_t)(nb + rr) * 16 + seg * 4 + q]
                           : make_float4(0.f, 0.f, 0.f, 0.f);
                lds_f4[(rr * FPAD + seg * 16 + q * 4) >> 2] = v;
            }
            __syncthreads();
            float acc[4][4];
            #pragma unroll
            for (int i = 0; i < 4; ++i)
                #pragma unroll
                for (int j = 0; j < 4; ++j) acc[i][j] = 0.f;
            for (int k0 = 0; k0 < DIM; k0 += 4) {
                float4 hv[4], wv[4];
                #pragma unroll
                for (int i = 0; i < 4; ++i)
                    hv[i] = lds_f4[((ny * 4 + i) * FPAD + k0) >> 2];
                #pragma unroll
                for (int j = 0; j < 4; ++j)
                    wv[j] = lds_w4[((k0 + j) * DIM + tx * 4) >> 2];
                #pragma unroll
                for (int i = 0; i < 4; ++i) {
                    const float* hp = (const float*)&hv[i];
                    #pragma unroll
                    for (int kk = 0; kk < 4; ++kk) {
                        float hk = hp[kk];
                        acc[i][0] = fmaf(hk, ((const float*)&wv[kk])[0], acc[i][0]);
                        acc[i][1] = fmaf(hk, ((const float*)&wv[kk])[1], acc[i][1]);
                        acc[i][2] = fmaf(hk, ((const float*)&wv[kk])[2], acc[i][2]);
                        acc[i][3] = fmaf(hk, ((const float*)&wv[kk])[3], acc[i][3]);
                    }
                }
            }
            #pragma unroll
            for (int i = 0; i < 4; ++i) {
                int node = nb + ny * 4 + i;
                if (node < N_NODES) {
                    ushort4 o;
                    o.x = (unsigned short)bf16_rne(acc[i][0]);
                    o.y = (unsigned short)bf16_rne(acc[i][1]);
                    o.z = (unsigned short)bf16_rne(acc[i][2]);
                    o.w = (unsigned short)bf16_rne(acc[i][3]);
                    *(ushort4*)(fW + (size_t)node * DIM + tx * 4) = o;
                }
            }
        }
    }
}

// ---- per-bin in-LDS counting sort -> packed CSR (src17|w15), offs, cnt ----
// 512 threads: halves the histogram/scatter/flush strided loops vs 256.
__global__ __launch_bounds__(512) void k_sortbin(const uint2* __restrict__ binned,
                                                 const int* __restrict__ cursor,
                                                 unsigned* __restrict__ csrp,
                                                 int* __restrict__ offs,
                                                 int* __restrict__ cnt) {
    __shared__ int h[256];
    __shared__ int excl[256];
    __shared__ unsigned stage[CAP];
    int b = blockIdx.x, t = threadIdx.x;
    int total = cursor[b];
    int segbase = b * CAP;
    if (t < 256) h[t] = 0;
    __syncthreads();
    for (int i = t; i < total; i += 512)
        atomicAdd(&h[(binned[segbase + i].x >> 17) & 255], 1);
    __syncthreads();
    int v = 0;
    if (t < 256) { v = h[t]; excl[t] = v; }
    __syncthreads();
    for (int off = 1; off < 256; off <<= 1) {
        int add = 0;
        if (t < 256 && t >= off) add = excl[t - off];
        __syncthreads();
        if (t < 256) excl[t] += add;
        __syncthreads();
    }
    if (t < 256) {
        int ex = excl[t] - v;
        excl[t] = ex;
        int node = (b << 8) + t;
        if (node < N_NODES) { cnt[node] = v; offs[node] = segbase + ex; }
        h[t] = 0;   // reuse as per-node cursor
    }
    __syncthreads();
    for (int i = t; i < total; i += 512) {
        uint2 e = binned[segbase + i];
        int o = (e.x >> 17) & 255;
        int pos = excl[o] + atomicAdd(&h[o], 1);
        if (pos < CAP) stage[pos] = (e.x & 0x1ffffu) | (e.y << 17);
    }
    __syncthreads();
    for (int i = t; i < total; i += 512)
        csrp[segbase + i] = stage[i];   // coalesced flush
}

// ---- gather fW rows per node, normalize, store ----
// wave = node; 8 groups of 8 lanes; lane s covers dims 8s..8s+7 (uint4 = 16B load).
// 32 edges per round (4 rows in flight per lane): deg<=32 (99.99% of nodes)
// completes in ONE latency round.
__global__ __launch_bounds__(256) void k_gather(const uint4* __restrict__ fW4,
                                                const unsigned* __restrict__ csrp,
                                                const int* __restrict__ offs,
                                                const int* __restrict__ cnt,
                                                float* __restrict__ out) {
    int lane = threadIdx.x & 63;
    int g = lane >> 3, s = lane & 7;
    int wave = (blockIdx.x * 256 + threadIdx.x) >> 6;
    int nw = gridDim.x * 4;

    for (int node = wave; node < N_NODES; node += nw) {
        int start = offs[node];
        int c = cnt[node];
        int end = start + c;
        float a[8] = {0, 0, 0, 0, 0, 0, 0, 0};
        for (int i = start; i < end; i += 32) {
            int i0 = i + g, i1 = i + 8 + g, i2 = i + 16 + g, i3 = i + 24 + g;
            unsigned p0 = csrp[(i0 < end) ? i0 : start];
            unsigned p1 = csrp[(i1 < end) ? i1 : start];
            unsigned p2 = csrp[(i2 < end) ? i2 : start];
            unsigned p3 = csrp[(i3 < end) ? i3 : start];
            float w0 = (i0 < end) ? (float)(p0 >> 17) * WSCALE : 0.f;
            float w1 = (i1 < end) ? (float)(p1 >> 17) * WSCALE : 0.f;
            float w2 = (i2 < end) ? (float)(p2 >> 17) * WSCALE : 0.f;
            float w3 = (i3 < end) ? (float)(p3 >> 17) * WSCALE : 0.f;
            uint4 q0 = fW4[((p0 & 0x1ffffu) << 3) + s];
            uint4 q1 = fW4[((p1 & 0x1ffffu) << 3) + s];
            uint4 q2 = fW4[((p2 & 0x1ffffu) << 3) + s];
            uint4 q3 = fW4[((p3 & 0x1ffffu) << 3) + s];
            a[0] = fmaf(bf_lo(q0.x), w0, a[0]); a[1] = fmaf(bf_hi(q0.x), w0, a[1]);
            a[2] = fmaf(bf_lo(q0.y), w0, a[2]); a[3] = fmaf(bf_hi(q0.y), w0, a[3]);
            a[4] = fmaf(bf_lo(q0.z), w0, a[4]); a[5] = fmaf(bf_hi(q0.z), w0, a[5]);
            a[6] = fmaf(bf_lo(q0.w), w0, a[6]); a[7] = fmaf(bf_hi(q0.w), w0, a[7]);
            a[0] = fmaf(bf_lo(q1.x), w1, a[0]); a[1] = fmaf(bf_hi(q1.x), w1, a[1]);
            a[2] = fmaf(bf_lo(q1.y), w1, a[2]); a[3] = fmaf(bf_hi(q1.y), w1, a[3]);
            a[4] = fmaf(bf_lo(q1.z), w1, a[4]); a[5] = fmaf(bf_hi(q1.z), w1, a[5]);
            a[6] = fmaf(bf_lo(q1.w), w1, a[6]); a[7] = fmaf(bf_hi(q1.w), w1, a[7]);
            a[0] = fmaf(bf_lo(q2.x), w2, a[0]); a[1] = fmaf(bf_hi(q2.x), w2, a[1]);
            a[2] = fmaf(bf_lo(q2.y), w2, a[2]); a[3] = fmaf(bf_hi(q2.y), w2, a[3]);
            a[4] = fmaf(bf_lo(q2.z), w2, a[4]); a[5] = fmaf(bf_hi(q2.z), w2, a[5]);
            a[6] = fmaf(bf_lo(q2.w), w2, a[6]); a[7] = fmaf(bf_hi(q2.w), w2, a[7]);
            a[0] = fmaf(bf_lo(q3.x), w3, a[0]); a[1] = fmaf(bf_hi(q3.x), w3, a[1]);
            a[2] = fmaf(bf_lo(q3.y), w3, a[2]); a[3] = fmaf(bf_hi(q3.y), w3, a[3]);
            a[4] = fmaf(bf_lo(q3.z), w3, a[4]); a[5] = fmaf(bf_hi(q3.z), w3, a[5]);
            a[6] = fmaf(bf_lo(q3.w), w3, a[6]); a[7] = fmaf(bf_hi(q3.w), w3, a[7]);
        }
        #pragma unroll
        for (int j = 0; j < 8; ++j) {
            a[j] += __shfl_xor(a[j], 8, 64);
            a[j] += __shfl_xor(a[j], 16, 64);
            a[j] += __shfl_xor(a[j], 32, 64);
        }
        float dinv = 1.0f / fmaxf((float)c, 1.0f);
        if (g == 0) {   // lanes 0..7: lane s holds dims 8s..8s+7
            float4 o0, o1;
            o0.x = a[0] * dinv; o0.y = a[1] * dinv; o0.z = a[2] * dinv; o0.w = a[3] * dinv;
            o1.x = a[4] * dinv; o1.y = a[5] * dinv; o1.z = a[6] * dinv; o1.w = a[7] * dinv;
            ((float4*)out)[node * 16 + s * 2 + 0] = o0;
            ((float4*)out)[node * 16 + s * 2 + 1] = o1;
        }
    }
}

extern "C" void kernel_launch(void* const* d_in, const int* in_sizes, int n_in,
                              void* d_out, int out_size, void* d_ws, size_t ws_size,
                              hipStream_t stream) {
    const float* feat = (const float*)d_in[0];
    const float* w    = (const float*)d_in[1];
    const float* W    = (const float*)d_in[2];
    const int*   src  = (const int*)d_in[3];
    const int*   dst  = (const int*)d_in[4];
    float* out = (float*)d_out;

    // No aliasing (fill and conv overlap). ~31 MB total, ws is 256 MiB.
    unsigned short* fW = (unsigned short*)d_ws;                  // 12.8 MB, 16B-aligned
    uint2* binned  = (uint2*)(fW + (size_t)N_NODES * DIM);       // NBINS*CAP*8 = 11.6 MB
    unsigned* csrp = (unsigned*)(binned + (size_t)NBINS * CAP);  // 5.8 MB
    int* offs      = (int*)(csrp + (size_t)NBINS * CAP);         // N_NODES
    int* cnt       = offs + N_NODES;                             // N_NODES
    int* cursor    = cnt + N_NODES;                              // NBINS

    hipMemsetAsync(cursor, 0, NBINS * sizeof(int), stream);

    k_fill_conv<<<NFB + CONVB, 256, 0, stream>>>(src, w, dst, cursor, binned,
                                                 feat, W, fW);
    k_sortbin<<<NBINS, 512, 0, stream>>>(binned, cursor, csrp, offs, cnt);
    k_gather<<<4096, 256, 0, stream>>>((const uint4*)fW, csrp, offs, cnt, out);
}